// Round 6
// baseline (269.283 us; speedup 1.0000x reference)
//
#include <hip/hip_runtime.h>
#include <math.h>

// Problem constants (match reference file).
#define BATCH 256
#define VOCAB 128000
#define HIST  2048
#define EPS_T 1e-5f

#define MASK_WORDS_ROW (VOCAB / 32)    // 4000 words = 16 KB per row

// --- kernel A: presence bitmask per row ---
#define ABLOCK 512

// --- kernel B: scan ---
#define SEGS 25
#define SEG_ELEMS (VOCAB / SEGS)       // 5120 elements per block
#define SEG_VEC   (SEG_ELEMS / 4)      // 1280 float4s per block
#define SEG_WORDS (SEG_ELEMS / 32)     // 160 mask words per block
#define BBLOCK 256
#define BWAVES 4
#define WV_F4   (SEG_VEC / BWAVES)     // 320 float4s per wave
#define CHUNKS  (WV_F4 / 64)           // 5 chunks of 64 float4s per wave
#define WV_WORDS (SEG_WORDS / BWAVES)  // 40 mask words per wave

__global__ __launch_bounds__(ABLOCK, 1) void mask_kernel(
    const int* __restrict__ token_ids,       // [B, L]
    unsigned int* __restrict__ gmask)        // [B, MASK_WORDS_ROW]
{
    __shared__ unsigned int m[MASK_WORDS_ROW];
    const int b = blockIdx.x, tid = threadIdx.x;

    for (int i = tid; i < MASK_WORDS_ROW; i += ABLOCK) m[i] = 0u;
    __syncthreads();

    // 2048 tokens / 512 threads = one int4 load per thread
    const int4* rt = (const int4*)(token_ids + (size_t)b * HIST);
    int4 t = rt[tid];
    atomicOr(&m[t.x >> 5], 1u << (t.x & 31));
    atomicOr(&m[t.y >> 5], 1u << (t.y & 31));
    atomicOr(&m[t.z >> 5], 1u << (t.z & 31));
    atomicOr(&m[t.w >> 5], 1u << (t.w & 31));
    __syncthreads();

    unsigned int* gr = gmask + (size_t)b * MASK_WORDS_ROW;
    for (int i = tid; i < MASK_WORDS_ROW; i += ABLOCK) gr[i] = m[i];
}

__device__ __forceinline__ void upd(float s, int idx, float& best, int& besti) {
    if (s > best || (s == best && idx < besti)) { best = s; besti = idx; }
}

// Async 16B global->LDS DMA. No destination VGPRs: the compiler cannot sink
// or serialize this against uses (rounds 3-5 showed every VGPR-destined load
// burst gets re-serialized by the scheduler/MachineSink; VGPR stuck at 32).
// LDS dest is wave-uniform base; lane i's 16B lands at base + i*16.
__device__ __forceinline__ void cp16(const void* g, void* l) {
    __builtin_amdgcn_global_load_lds(
        (const __attribute__((address_space(1))) void*)g,
        (__attribute__((address_space(3))) void*)l, 16, 0, 0);
}

__global__ __launch_bounds__(BBLOCK, 1) void scan_kernel(
    const float* __restrict__ logits,        // [B, V]
    const float* __restrict__ gumbel,        // [B, V]
    const unsigned int* __restrict__ gmask,  // [B, MASK_WORDS_ROW]
    const float* __restrict__ penalties,     // [B]
    const float* __restrict__ temps,         // [B]
    float* __restrict__ pvals,               // [SEGS][B]
    int*   __restrict__ pidxs)               // [SEGS][B]
{
    // 40960 B total -> exactly 4 blocks/CU (160 KiB LDS). Per-wave reduction
    // results are aliased into sl (consumed by then) to avoid extra LDS.
    __shared__ float4 sl[SEG_VEC];           // 20 KiB staged logits
    __shared__ float4 sg[SEG_VEC];           // 20 KiB staged gumbel

    const int blk = blockIdx.x;
    const int b   = blk / SEGS;
    const int seg = blk - b * SEGS;
    const int tid = threadIdx.x;
    const int w   = tid >> 6;                // wave id (uniform per wave)
    const int l   = tid & 63;                // lane

    const float pen    = penalties[b];
    const float temp   = temps[b];
    const bool  greedy = (temp < EPS_T);

    const float4*       lg = (const float4*)(logits + (size_t)b * VOCAB) + seg * SEG_VEC;
    const float4*       gm = (const float4*)(gumbel + (size_t)b * VOCAB) + seg * SEG_VEC;
    const unsigned int* mw = gmask + (size_t)b * MASK_WORDS_ROW + seg * SEG_WORDS;

    const int base = w * WV_F4;              // this wave's float4 region

    // mask words for this wave's 5 chunks (VGPR loads; overlap the DMA)
    const int wb = w * WV_WORDS + (l >> 3);
    unsigned mk[CHUNKS];
    #pragma unroll
    for (int c = 0; c < CHUNKS; c++) mk[c] = mw[wb + c * 8];

    // wave-private async staging: 5 (or 10) x 1KB DMAs in flight, 0 VGPRs
    #pragma unroll
    for (int c = 0; c < CHUNKS; c++)
        cp16(&lg[base + c * 64 + l], &sl[base + c * 64]);
    if (!greedy) {
        #pragma unroll
        for (int c = 0; c < CHUNKS; c++)
            cp16(&gm[base + c * 64 + l], &sg[base + c * 64]);
    }
    __builtin_amdgcn_s_waitcnt(0);           // drain this wave's vmcnt
    __builtin_amdgcn_sched_barrier(0);

    float best  = -INFINITY;
    int   besti = 0x7fffffff;
    const int sh   = (l * 4) & 31;           // bit offset, uniform across chunks
    const int abs0 = seg * SEG_ELEMS;

    if (greedy) {
        #pragma unroll
        for (int c = 0; c < CHUNKS; c++) {
            const int fv = base + c * 64 + l;          // float4 index in segment
            float4 L = sl[fv];
            float e[4] = {L.x, L.y, L.z, L.w};
            #pragma unroll
            for (int j = 0; j < 4; j++) {
                float present = (float)((mk[c] >> (sh + j)) & 1u);
                float p = e[j] - pen * present;        // exact: present in {0,1}
                upd(p, abs0 + fv * 4 + j, best, besti);
            }
        }
    } else {
        #pragma unroll
        for (int c = 0; c < CHUNKS; c++) {
            const int fv = base + c * 64 + l;
            float4 L = sl[fv];
            float4 G = sg[fv];
            float e[4]  = {L.x, L.y, L.z, L.w};
            float gv[4] = {G.x, G.y, G.z, G.w};
            #pragma unroll
            for (int j = 0; j < 4; j++) {
                float present = (float)((mk[c] >> (sh + j)) & 1u);
                float p = e[j] - pen * present;
                float s = p / temp + gv[j];            // reference op order, IEEE div
                upd(s, abs0 + fv * 4 + j, best, besti);
            }
        }
    }

    // wave argmax reduction (64 lanes), first-index tie-break
    #pragma unroll
    for (int off = 32; off > 0; off >>= 1) {
        float ov = __shfl_down(best, off, 64);
        int   oi = __shfl_down(besti, off, 64);
        if (ov > best || (ov == best && oi < besti)) { best = ov; besti = oi; }
    }

    // lane 0 parks the wave result in its own (fully consumed) staging slot
    if (l == 0) {
        float2 r = make_float2(best, __int_as_float(besti));
        *(float2*)&sl[base] = r;
    }
    __syncthreads();

    if (tid == 0) {
        #pragma unroll
        for (int wv = 1; wv < BWAVES; wv++) {
            float2 r = *(float2*)&sl[wv * WV_F4];
            int ri = __float_as_int(r.y);
            if (r.x > best || (r.x == best && ri < besti)) { best = r.x; besti = ri; }
        }
        pvals[seg * BATCH + b] = best;    // [seg][row] -> coalesced reduce
        pidxs[seg * BATCH + b] = besti;
    }
}

__global__ void reduce_kernel(const float* __restrict__ pvals,
                              const int*   __restrict__ pidxs,
                              int*         __restrict__ out)
{
    const int b = threadIdx.x;            // 256 threads, one per row
    float best  = pvals[b];
    int   besti = pidxs[b];
    #pragma unroll
    for (int s = 1; s < SEGS; s++) {
        float v = pvals[s * BATCH + b];
        // strictly greater wins: ascending seg = ascending indices = numpy tie-break
        if (v > best) { best = v; besti = pidxs[s * BATCH + b]; }
    }
    out[b] = besti;
}

extern "C" void kernel_launch(void* const* d_in, const int* in_sizes, int n_in,
                              void* d_out, int out_size, void* d_ws, size_t ws_size,
                              hipStream_t stream) {
    const float* logits    = (const float*)d_in[0];
    const int*   token_ids = (const int*)d_in[1];
    const float* penalties = (const float*)d_in[2];
    const float* temps     = (const float*)d_in[3];
    const float* gumbel    = (const float*)d_in[4];
    int* out = (int*)d_out;

    unsigned int* gmask = (unsigned int*)d_ws;                       // 4,096,000 B
    float* pvals = (float*)((char*)d_ws + (size_t)BATCH * MASK_WORDS_ROW * 4);
    int*   pidxs = (int*)(pvals + SEGS * BATCH);

    mask_kernel<<<BATCH, ABLOCK, 0, stream>>>(token_ids, gmask);
    scan_kernel<<<BATCH * SEGS, BBLOCK, 0, stream>>>(logits, gumbel, gmask,
                                                     penalties, temps, pvals, pidxs);
    reduce_kernel<<<1, BATCH, 0, stream>>>(pvals, pidxs, out);
}